// Round 1
// baseline (1053.088 us; speedup 1.0000x reference)
//
#include <hip/hip_runtime.h>

#define N_ROIS 512
#define P_PTS  128
#define C_CH   256

__global__ __launch_bounds__(256) void mpe_sample_kernel(
    const float* __restrict__ feat0, const float* __restrict__ feat1,
    const float* __restrict__ feat2, const float* __restrict__ feat3,
    const float* __restrict__ rois,  const float* __restrict__ points,
    float* __restrict__ out)
{
    const int blk = blockIdx.x;      // n*4 + lvl
    const int n   = blk >> 2;
    const int lvl = blk & 3;

    const float* feat;
    int H;
    float inv_stride;
    if      (lvl == 0) { feat = feat0; H = 256; inv_stride = 0.25f;    }
    else if (lvl == 1) { feat = feat1; H = 128; inv_stride = 0.125f;   }
    else if (lvl == 2) { feat = feat2; H = 64;  inv_stride = 0.0625f;  }
    else               { feat = feat3; H = 32;  inv_stride = 0.03125f; }
    const int W  = H;
    const int HW = H * W;

    __shared__ int   s_off[4][P_PTS];
    __shared__ float s_w[4][P_PTS];

    const int tid = threadIdx.x;

    // Phase 1: per-point bilinear setup (channel-invariant), threads 0..127
    if (tid < P_PTS) {
        const int p = tid;
        const float bx = rois[n * 5 + 0];
        const float x1 = rois[n * 5 + 1];
        const float y1 = rois[n * 5 + 2];
        const float x2 = rois[n * 5 + 3];
        const float y2 = rois[n * 5 + 4];
        const float ptx = points[(n * P_PTS + p) * 2 + 0];
        const float pty = points[(n * P_PTS + p) * 2 + 1];

        const float cx = x1 + ptx * (x2 - x1);
        const float cy = y1 + pty * (y2 - y1);
        const float px = cx * inv_stride - 0.5f;
        const float py = cy * inv_stride - 0.5f;
        const float x0f = floorf(px);
        const float y0f = floorf(py);
        const float wx = px - x0f;
        const float wy = py - y0f;
        const int x0 = (int)x0f;
        const int y0 = (int)y0f;
        const int b  = (int)bx;
        const int base = b * C_CH * HW;

        #pragma unroll
        for (int k = 0; k < 4; ++k) {
            const int xi = x0 + (k & 1);
            const int yi = y0 + (k >> 1);
            const bool valid = (xi >= 0) & (xi < W) & (yi >= 0) & (yi < H);
            const int xc = min(max(xi, 0), W - 1);
            const int yc = min(max(yi, 0), H - 1);
            const float wk = ((k & 1) ? wx : 1.0f - wx) *
                             ((k >> 1) ? wy : 1.0f - wy);
            s_off[k][p] = base + yc * W + xc;
            s_w[k][p]   = valid ? wk : 0.0f;
        }
    }
    __syncthreads();

    // Phase 2: thread = (p fast, c-subgroup slow); walk channels.
    const int p  = tid & (P_PTS - 1);
    const int c0 = tid >> 7;   // 0 or 1

    const int   off0 = s_off[0][p], off1 = s_off[1][p],
                off2 = s_off[2][p], off3 = s_off[3][p];
    const float w0 = s_w[0][p], w1 = s_w[1][p],
                w2 = s_w[2][p], w3 = s_w[3][p];

    const float* p0 = feat + off0 + c0 * HW;
    const float* p1 = feat + off1 + c0 * HW;
    const float* p2 = feat + off2 + c0 * HW;
    const float* p3 = feat + off3 + c0 * HW;
    float* po = out + ((size_t)n * 1024 + (size_t)lvl * 256 + c0) * P_PTS + p;

    const int step = 2 * HW;
    #pragma unroll 4
    for (int pass = 0; pass < C_CH / 2; ++pass) {
        const float v = p0[0] * w0 + p1[0] * w1 + p2[0] * w2 + p3[0] * w3;
        *po = v;
        p0 += step; p1 += step; p2 += step; p3 += step;
        po += 2 * P_PTS;
    }
}

extern "C" void kernel_launch(void* const* d_in, const int* in_sizes, int n_in,
                              void* d_out, int out_size, void* d_ws, size_t ws_size,
                              hipStream_t stream) {
    const float* feat0  = (const float*)d_in[0];
    const float* feat1  = (const float*)d_in[1];
    const float* feat2  = (const float*)d_in[2];
    const float* feat3  = (const float*)d_in[3];
    const float* rois   = (const float*)d_in[4];
    const float* points = (const float*)d_in[5];
    float* out = (float*)d_out;

    dim3 grid(N_ROIS * 4);
    dim3 block(256);
    mpe_sample_kernel<<<grid, block, 0, stream>>>(feat0, feat1, feat2, feat3,
                                                  rois, points, out);
}

// Round 2
// 572.856 us; speedup vs baseline: 1.8383x; 1.8383x over previous
//
#include <hip/hip_runtime.h>

#define N_ROIS 512
#define P_PTS  128
#define C_CH   256

// ---- transposed-level float offsets in workspace ----
// L0: 2*256*256*256  L1: 2*256*128*128  L2: 2*256*64*64  L3: 2*256*32*32
#define L0_OFS 0
#define L1_OFS 33554432u
#define L2_OFS 41943040u
#define L3_OFS 44040192u
#define WS_FLOATS_NEEDED 44564480u   // *4 = 178,257,920 bytes

// ---------------- NCHW -> NHWC tiled transpose (per level) ----------------
__global__ __launch_bounds__(256) void transpose_nchw_nhwc(
    const float* __restrict__ in, float* __restrict__ out, int HW)
{
    __shared__ float tile[32][33];
    const int pix0 = blockIdx.x * 32;
    const int c0   = blockIdx.y * 32;
    const int b    = blockIdx.z;
    in  += (size_t)b * C_CH * HW;
    out += (size_t)b * C_CH * HW;
    const int tx = threadIdx.x;   // 0..31
    const int ty = threadIdx.y;   // 0..7

    #pragma unroll
    for (int i = 0; i < 32; i += 8)
        tile[ty + i][tx] = in[(size_t)(c0 + ty + i) * HW + pix0 + tx];
    __syncthreads();
    #pragma unroll
    for (int i = 0; i < 32; i += 8)
        out[(size_t)(pix0 + ty + i) * C_CH + c0 + tx] = tile[tx][ty + i];
}

// ---------------- sampler over NHWC feats ----------------
__global__ __launch_bounds__(256) void mpe_sample_nhwc(
    const float* __restrict__ fT,
    const float* __restrict__ rois, const float* __restrict__ points,
    float* __restrict__ out)
{
    const int blk = blockIdx.x;      // n*4 + lvl
    const int n   = blk >> 2;
    const int lvl = blk & 3;

    int H; float inv_stride; size_t lofs;
    if      (lvl == 0) { H = 256; inv_stride = 0.25f;    lofs = L0_OFS; }
    else if (lvl == 1) { H = 128; inv_stride = 0.125f;   lofs = L1_OFS; }
    else if (lvl == 2) { H = 64;  inv_stride = 0.0625f;  lofs = L2_OFS; }
    else               { H = 32;  inv_stride = 0.03125f; lofs = L3_OFS; }
    const int W  = H;
    const int HW = H * W;
    const float* feat = fT + lofs;

    __shared__ int   s_off[P_PTS][4];   // pixel index incl. batch base
    __shared__ float s_w[P_PTS][4];

    const int tid = threadIdx.x;

    if (tid < P_PTS) {
        const int p = tid;
        const float bx = rois[n * 5 + 0];
        const float x1 = rois[n * 5 + 1];
        const float y1 = rois[n * 5 + 2];
        const float x2 = rois[n * 5 + 3];
        const float y2 = rois[n * 5 + 4];
        const float ptx = points[(n * P_PTS + p) * 2 + 0];
        const float pty = points[(n * P_PTS + p) * 2 + 1];

        const float cx = x1 + ptx * (x2 - x1);
        const float cy = y1 + pty * (y2 - y1);
        const float px = cx * inv_stride - 0.5f;
        const float py = cy * inv_stride - 0.5f;
        const float x0f = floorf(px);
        const float y0f = floorf(py);
        const float wx = px - x0f;
        const float wy = py - y0f;
        const int x0 = (int)x0f;
        const int y0 = (int)y0f;
        const int base = (int)bx * HW;

        #pragma unroll
        for (int k = 0; k < 4; ++k) {
            const int xi = x0 + (k & 1);
            const int yi = y0 + (k >> 1);
            const bool valid = (xi >= 0) & (xi < W) & (yi >= 0) & (yi < H);
            const int xc = min(max(xi, 0), W - 1);
            const int yc = min(max(yi, 0), H - 1);
            const float wk = ((k & 1) ? wx : 1.0f - wx) *
                             ((k >> 1) ? wy : 1.0f - wy);
            s_off[p][k] = base + yc * W + xc;
            s_w[p][k]   = valid ? wk : 0.0f;
        }
    }
    __syncthreads();

    // thread = channel c; lanes span contiguous channels -> coalesced gathers
    const int c = tid;
    float* po = out + ((size_t)n * 1024 + (size_t)lvl * 256 + c) * P_PTS;

    for (int p = 0; p < P_PTS; p += 4) {
        float acc[4];
        #pragma unroll
        for (int j = 0; j < 4; ++j) {
            const int pp = p + j;
            const float v0 = feat[(size_t)s_off[pp][0] * C_CH + c];
            const float v1 = feat[(size_t)s_off[pp][1] * C_CH + c];
            const float v2 = feat[(size_t)s_off[pp][2] * C_CH + c];
            const float v3 = feat[(size_t)s_off[pp][3] * C_CH + c];
            acc[j] = v0 * s_w[pp][0] + v1 * s_w[pp][1] +
                     v2 * s_w[pp][2] + v3 * s_w[pp][3];
        }
        *(float4*)(po + p) = make_float4(acc[0], acc[1], acc[2], acc[3]);
    }
}

// ---------------- fallback (R1 kernel) if workspace too small ----------------
__global__ __launch_bounds__(256) void mpe_sample_nchw(
    const float* __restrict__ feat0, const float* __restrict__ feat1,
    const float* __restrict__ feat2, const float* __restrict__ feat3,
    const float* __restrict__ rois,  const float* __restrict__ points,
    float* __restrict__ out)
{
    const int blk = blockIdx.x;
    const int n   = blk >> 2;
    const int lvl = blk & 3;

    const float* feat;
    int H; float inv_stride;
    if      (lvl == 0) { feat = feat0; H = 256; inv_stride = 0.25f;    }
    else if (lvl == 1) { feat = feat1; H = 128; inv_stride = 0.125f;   }
    else if (lvl == 2) { feat = feat2; H = 64;  inv_stride = 0.0625f;  }
    else               { feat = feat3; H = 32;  inv_stride = 0.03125f; }
    const int W  = H;
    const int HW = H * W;

    __shared__ int   s_off[4][P_PTS];
    __shared__ float s_w[4][P_PTS];
    const int tid = threadIdx.x;

    if (tid < P_PTS) {
        const int p = tid;
        const float bx = rois[n * 5 + 0];
        const float x1 = rois[n * 5 + 1];
        const float y1 = rois[n * 5 + 2];
        const float x2 = rois[n * 5 + 3];
        const float y2 = rois[n * 5 + 4];
        const float ptx = points[(n * P_PTS + p) * 2 + 0];
        const float pty = points[(n * P_PTS + p) * 2 + 1];
        const float cx = x1 + ptx * (x2 - x1);
        const float cy = y1 + pty * (y2 - y1);
        const float px = cx * inv_stride - 0.5f;
        const float py = cy * inv_stride - 0.5f;
        const float x0f = floorf(px);
        const float y0f = floorf(py);
        const float wx = px - x0f;
        const float wy = py - y0f;
        const int x0 = (int)x0f;
        const int y0 = (int)y0f;
        const int base = (int)bx * C_CH * HW;
        #pragma unroll
        for (int k = 0; k < 4; ++k) {
            const int xi = x0 + (k & 1);
            const int yi = y0 + (k >> 1);
            const bool valid = (xi >= 0) & (xi < W) & (yi >= 0) & (yi < H);
            const int xc = min(max(xi, 0), W - 1);
            const int yc = min(max(yi, 0), H - 1);
            const float wk = ((k & 1) ? wx : 1.0f - wx) *
                             ((k >> 1) ? wy : 1.0f - wy);
            s_off[k][p] = base + yc * W + xc;
            s_w[k][p]   = valid ? wk : 0.0f;
        }
    }
    __syncthreads();

    const int p  = tid & (P_PTS - 1);
    const int c0 = tid >> 7;
    const int   off0 = s_off[0][p], off1 = s_off[1][p],
                off2 = s_off[2][p], off3 = s_off[3][p];
    const float w0 = s_w[0][p], w1 = s_w[1][p],
                w2 = s_w[2][p], w3 = s_w[3][p];
    const float* p0 = feat + off0 + c0 * HW;
    const float* p1 = feat + off1 + c0 * HW;
    const float* p2 = feat + off2 + c0 * HW;
    const float* p3 = feat + off3 + c0 * HW;
    float* po = out + ((size_t)n * 1024 + (size_t)lvl * 256 + c0) * P_PTS + p;
    const int step = 2 * HW;
    #pragma unroll 4
    for (int pass = 0; pass < C_CH / 2; ++pass) {
        *po = p0[0] * w0 + p1[0] * w1 + p2[0] * w2 + p3[0] * w3;
        p0 += step; p1 += step; p2 += step; p3 += step;
        po += 2 * P_PTS;
    }
}

extern "C" void kernel_launch(void* const* d_in, const int* in_sizes, int n_in,
                              void* d_out, int out_size, void* d_ws, size_t ws_size,
                              hipStream_t stream) {
    const float* feat0  = (const float*)d_in[0];
    const float* feat1  = (const float*)d_in[1];
    const float* feat2  = (const float*)d_in[2];
    const float* feat3  = (const float*)d_in[3];
    const float* rois   = (const float*)d_in[4];
    const float* points = (const float*)d_in[5];
    float* out = (float*)d_out;

    if (ws_size >= (size_t)WS_FLOATS_NEEDED * 4u) {
        float* fT = (float*)d_ws;
        // per-level transposes: grid (HW/32, C/32, batch)
        transpose_nchw_nhwc<<<dim3(256 * 256 / 32, C_CH / 32, 2), dim3(32, 8), 0, stream>>>(
            feat0, fT + L0_OFS, 256 * 256);
        transpose_nchw_nhwc<<<dim3(128 * 128 / 32, C_CH / 32, 2), dim3(32, 8), 0, stream>>>(
            feat1, fT + L1_OFS, 128 * 128);
        transpose_nchw_nhwc<<<dim3(64 * 64 / 32, C_CH / 32, 2), dim3(32, 8), 0, stream>>>(
            feat2, fT + L2_OFS, 64 * 64);
        transpose_nchw_nhwc<<<dim3(32 * 32 / 32, C_CH / 32, 2), dim3(32, 8), 0, stream>>>(
            feat3, fT + L3_OFS, 32 * 32);
        mpe_sample_nhwc<<<dim3(N_ROIS * 4), dim3(256), 0, stream>>>(
            fT, rois, points, out);
    } else {
        mpe_sample_nchw<<<dim3(N_ROIS * 4), dim3(256), 0, stream>>>(
            feat0, feat1, feat2, feat3, rois, points, out);
    }
}

// Round 3
// 306.653 us; speedup vs baseline: 3.4341x; 1.8681x over previous
//
#include <hip/hip_runtime.h>

#define N_ROIS 512
#define P_PTS  128
#define C_CH   256
#define TILE_P 16

// ---- transposed-level float offsets in workspace ----
#define L0_OFS 0
#define L1_OFS 33554432u
#define L2_OFS 41943040u
#define L3_OFS 44040192u
#define WS_FLOATS_NEEDED 44564480u   // *4 = 178,257,920 bytes

// ---------------- NCHW -> NHWC tiled transpose (per level) ----------------
__global__ __launch_bounds__(256) void transpose_nchw_nhwc(
    const float* __restrict__ in, float* __restrict__ out, int HW)
{
    __shared__ float tile[32][33];
    const int pix0 = blockIdx.x * 32;
    const int c0   = blockIdx.y * 32;
    const int b    = blockIdx.z;
    in  += (size_t)b * C_CH * HW;
    out += (size_t)b * C_CH * HW;
    const int tx = threadIdx.x;
    const int ty = threadIdx.y;

    #pragma unroll
    for (int i = 0; i < 32; i += 8)
        tile[ty + i][tx] = in[(size_t)(c0 + ty + i) * HW + pix0 + tx];
    __syncthreads();
    #pragma unroll
    for (int i = 0; i < 32; i += 8)
        out[(size_t)(pix0 + ty + i) * C_CH + c0 + tx] = tile[tx][ty + i];
}

// ---------------- sampler v2: dwordx4 gathers + LDS store-transpose ----------------
__global__ __launch_bounds__(256) void mpe_sample_nhwc_v2(
    const float* __restrict__ fT,
    const float* __restrict__ rois, const float* __restrict__ points,
    float* __restrict__ out)
{
    const int blk = blockIdx.x;      // n*4 + lvl
    const int n   = blk >> 2;
    const int lvl = blk & 3;

    int H; float inv_stride; size_t lofs;
    if      (lvl == 0) { H = 256; inv_stride = 0.25f;    lofs = L0_OFS; }
    else if (lvl == 1) { H = 128; inv_stride = 0.125f;   lofs = L1_OFS; }
    else if (lvl == 2) { H = 64;  inv_stride = 0.0625f;  lofs = L2_OFS; }
    else               { H = 32;  inv_stride = 0.03125f; lofs = L3_OFS; }
    const int W  = H;
    const int HW = H * W;
    const float* feat = fT + lofs;

    __shared__ int   s_off[P_PTS][4];
    __shared__ float s_w[P_PTS][4];
    __shared__ float s_t[TILE_P][C_CH];   // 16 KB point-tile output staging

    const int tid = threadIdx.x;

    if (tid < P_PTS) {
        const int p = tid;
        const float bx = rois[n * 5 + 0];
        const float x1 = rois[n * 5 + 1];
        const float y1 = rois[n * 5 + 2];
        const float x2 = rois[n * 5 + 3];
        const float y2 = rois[n * 5 + 4];
        const float ptx = points[(n * P_PTS + p) * 2 + 0];
        const float pty = points[(n * P_PTS + p) * 2 + 1];

        const float cx = x1 + ptx * (x2 - x1);
        const float cy = y1 + pty * (y2 - y1);
        const float px = cx * inv_stride - 0.5f;
        const float py = cy * inv_stride - 0.5f;
        const float x0f = floorf(px);
        const float y0f = floorf(py);
        const float wx = px - x0f;
        const float wy = py - y0f;
        const int x0 = (int)x0f;
        const int y0 = (int)y0f;
        const int base = (int)bx * HW;

        #pragma unroll
        for (int k = 0; k < 4; ++k) {
            const int xi = x0 + (k & 1);
            const int yi = y0 + (k >> 1);
            const bool valid = (xi >= 0) & (xi < W) & (yi >= 0) & (yi < H);
            const int xc = min(max(xi, 0), W - 1);
            const int yc = min(max(yi, 0), H - 1);
            const float wk = ((k & 1) ? wx : 1.0f - wx) *
                             ((k >> 1) ? wy : 1.0f - wy);
            s_off[p][k] = base + yc * W + xc;
            s_w[p][k]   = valid ? wk : 0.0f;
        }
    }
    __syncthreads();

    const int wave = tid >> 6;
    const int lane = tid & 63;      // lane = channel-quad: channels lane*4..+3

    for (int tile = 0; tile < P_PTS / TILE_P; ++tile) {
        const int pbase = tile * TILE_P + wave * 4;

        // ---- gather phase: 16 dwordx4 loads issued up front ----
        float4 v[4][4];
        #pragma unroll
        for (int j = 0; j < 4; ++j) {
            const int pp = pbase + j;
            #pragma unroll
            for (int k = 0; k < 4; ++k)
                v[j][k] = *((const float4*)(feat + (size_t)s_off[pp][k] * C_CH) + lane);
        }

        float4 acc[4];
        #pragma unroll
        for (int j = 0; j < 4; ++j) {
            const int pp = pbase + j;
            const float w0 = s_w[pp][0], w1 = s_w[pp][1];
            const float w2 = s_w[pp][2], w3 = s_w[pp][3];
            acc[j].x = v[j][0].x * w0 + v[j][1].x * w1 + v[j][2].x * w2 + v[j][3].x * w3;
            acc[j].y = v[j][0].y * w0 + v[j][1].y * w1 + v[j][2].y * w2 + v[j][3].y * w3;
            acc[j].z = v[j][0].z * w0 + v[j][1].z * w1 + v[j][2].z * w2 + v[j][3].z * w3;
            acc[j].w = v[j][0].w * w0 + v[j][1].w * w1 + v[j][2].w * w2 + v[j][3].w * w3;
        }

        __syncthreads();   // previous tile's store-phase reads of s_t are done
        #pragma unroll
        for (int j = 0; j < 4; ++j)
            *((float4*)&s_t[wave * 4 + j][lane * 4]) = acc[j];
        __syncthreads();

        // ---- store phase: thread = channel, coalesced 64 B per thread ----
        float o[TILE_P];
        #pragma unroll
        for (int i = 0; i < TILE_P; ++i)
            o[i] = s_t[i][tid];
        float* ob = out + ((size_t)n * 1024 + (size_t)lvl * 256 + tid) * P_PTS
                        + tile * TILE_P;
        #pragma unroll
        for (int i = 0; i < TILE_P / 4; ++i)
            *((float4*)(ob + i * 4)) = make_float4(o[i*4], o[i*4+1], o[i*4+2], o[i*4+3]);
    }
}

// ---------------- fallback (R1 kernel) if workspace too small ----------------
__global__ __launch_bounds__(256) void mpe_sample_nchw(
    const float* __restrict__ feat0, const float* __restrict__ feat1,
    const float* __restrict__ feat2, const float* __restrict__ feat3,
    const float* __restrict__ rois,  const float* __restrict__ points,
    float* __restrict__ out)
{
    const int blk = blockIdx.x;
    const int n   = blk >> 2;
    const int lvl = blk & 3;

    const float* feat;
    int H; float inv_stride;
    if      (lvl == 0) { feat = feat0; H = 256; inv_stride = 0.25f;    }
    else if (lvl == 1) { feat = feat1; H = 128; inv_stride = 0.125f;   }
    else if (lvl == 2) { feat = feat2; H = 64;  inv_stride = 0.0625f;  }
    else               { feat = feat3; H = 32;  inv_stride = 0.03125f; }
    const int W  = H;
    const int HW = H * W;

    __shared__ int   s_off[4][P_PTS];
    __shared__ float s_w[4][P_PTS];
    const int tid = threadIdx.x;

    if (tid < P_PTS) {
        const int p = tid;
        const float bx = rois[n * 5 + 0];
        const float x1 = rois[n * 5 + 1];
        const float y1 = rois[n * 5 + 2];
        const float x2 = rois[n * 5 + 3];
        const float y2 = rois[n * 5 + 4];
        const float ptx = points[(n * P_PTS + p) * 2 + 0];
        const float pty = points[(n * P_PTS + p) * 2 + 1];
        const float cx = x1 + ptx * (x2 - x1);
        const float cy = y1 + pty * (y2 - y1);
        const float px = cx * inv_stride - 0.5f;
        const float py = cy * inv_stride - 0.5f;
        const float x0f = floorf(px);
        const float y0f = floorf(py);
        const float wx = px - x0f;
        const float wy = py - y0f;
        const int x0 = (int)x0f;
        const int y0 = (int)y0f;
        const int base = (int)bx * C_CH * HW;
        #pragma unroll
        for (int k = 0; k < 4; ++k) {
            const int xi = x0 + (k & 1);
            const int yi = y0 + (k >> 1);
            const bool valid = (xi >= 0) & (xi < W) & (yi >= 0) & (yi < H);
            const int xc = min(max(xi, 0), W - 1);
            const int yc = min(max(yi, 0), H - 1);
            const float wk = ((k & 1) ? wx : 1.0f - wx) *
                             ((k >> 1) ? wy : 1.0f - wy);
            s_off[k][p] = base + yc * W + xc;
            s_w[k][p]   = valid ? wk : 0.0f;
        }
    }
    __syncthreads();

    const int p  = tid & (P_PTS - 1);
    const int c0 = tid >> 7;
    const int   off0 = s_off[0][p], off1 = s_off[1][p],
                off2 = s_off[2][p], off3 = s_off[3][p];
    const float w0 = s_w[0][p], w1 = s_w[1][p],
                w2 = s_w[2][p], w3 = s_w[3][p];
    const float* p0 = feat + off0 + c0 * HW;
    const float* p1 = feat + off1 + c0 * HW;
    const float* p2 = feat + off2 + c0 * HW;
    const float* p3 = feat + off3 + c0 * HW;
    float* po = out + ((size_t)n * 1024 + (size_t)lvl * 256 + c0) * P_PTS + p;
    const int step = 2 * HW;
    #pragma unroll 4
    for (int pass = 0; pass < C_CH / 2; ++pass) {
        *po = p0[0] * w0 + p1[0] * w1 + p2[0] * w2 + p3[0] * w3;
        p0 += step; p1 += step; p2 += step; p3 += step;
        po += 2 * P_PTS;
    }
}

extern "C" void kernel_launch(void* const* d_in, const int* in_sizes, int n_in,
                              void* d_out, int out_size, void* d_ws, size_t ws_size,
                              hipStream_t stream) {
    const float* feat0  = (const float*)d_in[0];
    const float* feat1  = (const float*)d_in[1];
    const float* feat2  = (const float*)d_in[2];
    const float* feat3  = (const float*)d_in[3];
    const float* rois   = (const float*)d_in[4];
    const float* points = (const float*)d_in[5];
    float* out = (float*)d_out;

    if (ws_size >= (size_t)WS_FLOATS_NEEDED * 4u) {
        float* fT = (float*)d_ws;
        transpose_nchw_nhwc<<<dim3(256 * 256 / 32, C_CH / 32, 2), dim3(32, 8), 0, stream>>>(
            feat0, fT + L0_OFS, 256 * 256);
        transpose_nchw_nhwc<<<dim3(128 * 128 / 32, C_CH / 32, 2), dim3(32, 8), 0, stream>>>(
            feat1, fT + L1_OFS, 128 * 128);
        transpose_nchw_nhwc<<<dim3(64 * 64 / 32, C_CH / 32, 2), dim3(32, 8), 0, stream>>>(
            feat2, fT + L2_OFS, 64 * 64);
        transpose_nchw_nhwc<<<dim3(32 * 32 / 32, C_CH / 32, 2), dim3(32, 8), 0, stream>>>(
            feat3, fT + L3_OFS, 32 * 32);
        mpe_sample_nhwc_v2<<<dim3(N_ROIS * 4), dim3(256), 0, stream>>>(
            fT, rois, points, out);
    } else {
        mpe_sample_nchw<<<dim3(N_ROIS * 4), dim3(256), 0, stream>>>(
            feat0, feat1, feat2, feat3, rois, points, out);
    }
}

// Round 4
// 243.913 us; speedup vs baseline: 4.3175x; 1.2572x over previous
//
#include <hip/hip_runtime.h>
#include <hip/hip_bf16.h>

#define N_ROIS 512
#define P_PTS  128
#define C_CH   256
#define TILE_P 16

// ---- transposed bf16-level element offsets in workspace ----
#define L0_OFS 0
#define L1_OFS 33554432u
#define L2_OFS 41943040u
#define L3_OFS 44040192u
#define WS_ELEMS_NEEDED 44564480u   // *2 B = 89,128,960 bytes

__device__ inline unsigned pack_bf16x2(float lo, float hi) {
    __hip_bfloat162 h = __float22bfloat162_rn(make_float2(lo, hi));
    unsigned r;
    __builtin_memcpy(&r, &h, 4);
    return r;
}

// ---------------- NCHW f32 -> NHWC bf16 tiled transpose ----------------
__global__ __launch_bounds__(256) void transpose_nchw_nhwc_bf16(
    const float* __restrict__ in, unsigned short* __restrict__ out, int HW)
{
    __shared__ float tile[32][33];
    const int pix0 = blockIdx.x * 32;
    const int c0   = blockIdx.y * 32;
    const int b    = blockIdx.z;
    in  += (size_t)b * C_CH * HW;
    out += (size_t)b * C_CH * HW;
    const int tx = threadIdx.x;   // 0..31
    const int ty = threadIdx.y;   // 0..7

    #pragma unroll
    for (int i = 0; i < 32; i += 8)
        tile[ty + i][tx] = in[(size_t)(c0 + ty + i) * HW + pix0 + tx];
    __syncthreads();

    // write: each thread packs 4 consecutive channels of one pixel (8 B)
    const int tid2 = ty * 32 + tx;
    const int wpix = tid2 >> 3;      // 0..31
    const int wq   = tid2 & 7;       // channel quad 0..7 (32 channels/tile)
    const float a = tile[wq * 4 + 0][wpix];
    const float bb = tile[wq * 4 + 1][wpix];
    const float c = tile[wq * 4 + 2][wpix];
    const float d = tile[wq * 4 + 3][wpix];
    uint2 pk;
    pk.x = pack_bf16x2(a, bb);
    pk.y = pack_bf16x2(c, d);
    *((uint2*)(out + (size_t)(pix0 + wpix) * C_CH + c0 + wq * 4)) = pk;
}

// ---------------- sampler v3: bf16 NHWC, dwordx2 gathers ----------------
__global__ __launch_bounds__(256) void mpe_sample_nhwc_bf16(
    const unsigned short* __restrict__ fT,
    const float* __restrict__ rois, const float* __restrict__ points,
    float* __restrict__ out)
{
    const int blk = blockIdx.x;      // n*4 + lvl
    const int n   = blk >> 2;
    const int lvl = blk & 3;

    int H; float inv_stride; size_t lofs;
    if      (lvl == 0) { H = 256; inv_stride = 0.25f;    lofs = L0_OFS; }
    else if (lvl == 1) { H = 128; inv_stride = 0.125f;   lofs = L1_OFS; }
    else if (lvl == 2) { H = 64;  inv_stride = 0.0625f;  lofs = L2_OFS; }
    else               { H = 32;  inv_stride = 0.03125f; lofs = L3_OFS; }
    const int W  = H;
    const int HW = H * W;
    const unsigned short* feat = fT + lofs;

    __shared__ int   s_off[P_PTS][4];
    __shared__ float s_w[P_PTS][4];
    __shared__ float s_t[TILE_P][C_CH];   // 16 KB point-tile output staging

    const int tid = threadIdx.x;

    if (tid < P_PTS) {
        const int p = tid;
        const float bx = rois[n * 5 + 0];
        const float x1 = rois[n * 5 + 1];
        const float y1 = rois[n * 5 + 2];
        const float x2 = rois[n * 5 + 3];
        const float y2 = rois[n * 5 + 4];
        const float ptx = points[(n * P_PTS + p) * 2 + 0];
        const float pty = points[(n * P_PTS + p) * 2 + 1];

        const float cx = x1 + ptx * (x2 - x1);
        const float cy = y1 + pty * (y2 - y1);
        const float px = cx * inv_stride - 0.5f;
        const float py = cy * inv_stride - 0.5f;
        const float x0f = floorf(px);
        const float y0f = floorf(py);
        const float wx = px - x0f;
        const float wy = py - y0f;
        const int x0 = (int)x0f;
        const int y0 = (int)y0f;
        const int base = (int)bx * HW;

        #pragma unroll
        for (int k = 0; k < 4; ++k) {
            const int xi = x0 + (k & 1);
            const int yi = y0 + (k >> 1);
            const bool valid = (xi >= 0) & (xi < W) & (yi >= 0) & (yi < H);
            const int xc = min(max(xi, 0), W - 1);
            const int yc = min(max(yi, 0), H - 1);
            const float wk = ((k & 1) ? wx : 1.0f - wx) *
                             ((k >> 1) ? wy : 1.0f - wy);
            s_off[p][k] = base + yc * W + xc;
            s_w[p][k]   = valid ? wk : 0.0f;
        }
    }
    __syncthreads();

    const int wave = tid >> 6;
    const int lane = tid & 63;      // lane = channel-quad (4 bf16 = 8 B)

    for (int tile = 0; tile < P_PTS / TILE_P; ++tile) {
        const int pbase = tile * TILE_P + wave * 4;

        // ---- gather phase: 16 dwordx2 loads issued up front ----
        uint2 v[4][4];
        #pragma unroll
        for (int j = 0; j < 4; ++j) {
            const int pp = pbase + j;
            #pragma unroll
            for (int k = 0; k < 4; ++k)
                v[j][k] = *((const uint2*)(feat + (size_t)s_off[pp][k] * C_CH) + lane);
        }

        float4 acc[4];
        #pragma unroll
        for (int j = 0; j < 4; ++j) {
            const int pp = pbase + j;
            float4 a = make_float4(0.f, 0.f, 0.f, 0.f);
            #pragma unroll
            for (int k = 0; k < 4; ++k) {
                const float wk = s_w[pp][k];
                const float c0 = __uint_as_float(v[j][k].x << 16);
                const float c1 = __uint_as_float(v[j][k].x & 0xffff0000u);
                const float c2 = __uint_as_float(v[j][k].y << 16);
                const float c3 = __uint_as_float(v[j][k].y & 0xffff0000u);
                a.x = fmaf(c0, wk, a.x);
                a.y = fmaf(c1, wk, a.y);
                a.z = fmaf(c2, wk, a.z);
                a.w = fmaf(c3, wk, a.w);
            }
            acc[j] = a;
        }

        __syncthreads();   // previous tile's store-phase reads of s_t are done
        #pragma unroll
        for (int j = 0; j < 4; ++j)
            *((float4*)&s_t[wave * 4 + j][lane * 4]) = acc[j];
        __syncthreads();

        // ---- store phase: thread = channel, coalesced 64 B per thread ----
        float o[TILE_P];
        #pragma unroll
        for (int i = 0; i < TILE_P; ++i)
            o[i] = s_t[i][tid];
        float* ob = out + ((size_t)n * 1024 + (size_t)lvl * 256 + tid) * P_PTS
                        + tile * TILE_P;
        #pragma unroll
        for (int i = 0; i < TILE_P / 4; ++i)
            *((float4*)(ob + i * 4)) = make_float4(o[i*4], o[i*4+1], o[i*4+2], o[i*4+3]);
    }
}

// ---------------- fallback (R1 kernel) if workspace too small ----------------
__global__ __launch_bounds__(256) void mpe_sample_nchw(
    const float* __restrict__ feat0, const float* __restrict__ feat1,
    const float* __restrict__ feat2, const float* __restrict__ feat3,
    const float* __restrict__ rois,  const float* __restrict__ points,
    float* __restrict__ out)
{
    const int blk = blockIdx.x;
    const int n   = blk >> 2;
    const int lvl = blk & 3;

    const float* feat;
    int H; float inv_stride;
    if      (lvl == 0) { feat = feat0; H = 256; inv_stride = 0.25f;    }
    else if (lvl == 1) { feat = feat1; H = 128; inv_stride = 0.125f;   }
    else if (lvl == 2) { feat = feat2; H = 64;  inv_stride = 0.0625f;  }
    else               { feat = feat3; H = 32;  inv_stride = 0.03125f; }
    const int W  = H;
    const int HW = H * W;

    __shared__ int   s_off[4][P_PTS];
    __shared__ float s_w[4][P_PTS];
    const int tid = threadIdx.x;

    if (tid < P_PTS) {
        const int p = tid;
        const float bx = rois[n * 5 + 0];
        const float x1 = rois[n * 5 + 1];
        const float y1 = rois[n * 5 + 2];
        const float x2 = rois[n * 5 + 3];
        const float y2 = rois[n * 5 + 4];
        const float ptx = points[(n * P_PTS + p) * 2 + 0];
        const float pty = points[(n * P_PTS + p) * 2 + 1];
        const float cx = x1 + ptx * (x2 - x1);
        const float cy = y1 + pty * (y2 - y1);
        const float px = cx * inv_stride - 0.5f;
        const float py = cy * inv_stride - 0.5f;
        const float x0f = floorf(px);
        const float y0f = floorf(py);
        const float wx = px - x0f;
        const float wy = py - y0f;
        const int x0 = (int)x0f;
        const int y0 = (int)y0f;
        const int base = (int)bx * C_CH * HW;
        #pragma unroll
        for (int k = 0; k < 4; ++k) {
            const int xi = x0 + (k & 1);
            const int yi = y0 + (k >> 1);
            const bool valid = (xi >= 0) & (xi < W) & (yi >= 0) & (yi < H);
            const int xc = min(max(xi, 0), W - 1);
            const int yc = min(max(yi, 0), H - 1);
            const float wk = ((k & 1) ? wx : 1.0f - wx) *
                             ((k >> 1) ? wy : 1.0f - wy);
            s_off[k][p] = base + yc * W + xc;
            s_w[k][p]   = valid ? wk : 0.0f;
        }
    }
    __syncthreads();

    const int p  = tid & (P_PTS - 1);
    const int c0 = tid >> 7;
    const int   off0 = s_off[0][p], off1 = s_off[1][p],
                off2 = s_off[2][p], off3 = s_off[3][p];
    const float w0 = s_w[0][p], w1 = s_w[1][p],
                w2 = s_w[2][p], w3 = s_w[3][p];
    const float* p0 = feat + off0 + c0 * HW;
    const float* p1 = feat + off1 + c0 * HW;
    const float* p2 = feat + off2 + c0 * HW;
    const float* p3 = feat + off3 + c0 * HW;
    float* po = out + ((size_t)n * 1024 + (size_t)lvl * 256 + c0) * P_PTS + p;
    const int step = 2 * HW;
    #pragma unroll 4
    for (int pass = 0; pass < C_CH / 2; ++pass) {
        *po = p0[0] * w0 + p1[0] * w1 + p2[0] * w2 + p3[0] * w3;
        p0 += step; p1 += step; p2 += step; p3 += step;
        po += 2 * P_PTS;
    }
}

extern "C" void kernel_launch(void* const* d_in, const int* in_sizes, int n_in,
                              void* d_out, int out_size, void* d_ws, size_t ws_size,
                              hipStream_t stream) {
    const float* feat0  = (const float*)d_in[0];
    const float* feat1  = (const float*)d_in[1];
    const float* feat2  = (const float*)d_in[2];
    const float* feat3  = (const float*)d_in[3];
    const float* rois   = (const float*)d_in[4];
    const float* points = (const float*)d_in[5];
    float* out = (float*)d_out;

    if (ws_size >= (size_t)WS_ELEMS_NEEDED * 2u) {
        unsigned short* fT = (unsigned short*)d_ws;
        transpose_nchw_nhwc_bf16<<<dim3(256 * 256 / 32, C_CH / 32, 2), dim3(32, 8), 0, stream>>>(
            feat0, fT + L0_OFS, 256 * 256);
        transpose_nchw_nhwc_bf16<<<dim3(128 * 128 / 32, C_CH / 32, 2), dim3(32, 8), 0, stream>>>(
            feat1, fT + L1_OFS, 128 * 128);
        transpose_nchw_nhwc_bf16<<<dim3(64 * 64 / 32, C_CH / 32, 2), dim3(32, 8), 0, stream>>>(
            feat2, fT + L2_OFS, 64 * 64);
        transpose_nchw_nhwc_bf16<<<dim3(32 * 32 / 32, C_CH / 32, 2), dim3(32, 8), 0, stream>>>(
            feat3, fT + L3_OFS, 32 * 32);
        mpe_sample_nhwc_bf16<<<dim3(N_ROIS * 4), dim3(256), 0, stream>>>(
            fT, rois, points, out);
    } else {
        mpe_sample_nchw<<<dim3(N_ROIS * 4), dim3(256), 0, stream>>>(
            feat0, feat1, feat2, feat3, rois, points, out);
    }
}

// Round 5
// 212.391 us; speedup vs baseline: 4.9583x; 1.1484x over previous
//
#include <hip/hip_runtime.h>
#include <hip/hip_bf16.h>

#define N_ROIS 512
#define P_PTS  128
#define C_CH   256
#define TILE_P 32

// ---- transposed bf16-level element offsets in workspace ----
#define L0_OFS 0
#define L1_OFS 33554432u
#define L2_OFS 41943040u
#define L3_OFS 44040192u
#define WS_ELEMS_NEEDED 44564480u   // *2 B = 89,128,960 bytes

__device__ inline unsigned pack_bf16x2(float lo, float hi) {
    __hip_bfloat162 h = __float22bfloat162_rn(make_float2(lo, hi));
    unsigned r;
    __builtin_memcpy(&r, &h, 4);
    return r;
}

// ---------------- fused NCHW f32 -> NHWC bf16 transpose (all 4 levels) ----------------
// grid.x = 2048 + 512 + 128 + 32 = 2720 pixel-tiles; grid.y = 8 channel groups; grid.z = 2
__global__ __launch_bounds__(256) void transpose_all_bf16(
    const float* __restrict__ f0, const float* __restrict__ f1,
    const float* __restrict__ f2, const float* __restrict__ f3,
    unsigned short* __restrict__ ws)
{
    const float* in; unsigned short* outp; int HW, pt;
    const int px = blockIdx.x;
    if (px < 2048)      { in = f0; outp = ws + L0_OFS; HW = 65536; pt = px; }
    else if (px < 2560) { in = f1; outp = ws + L1_OFS; HW = 16384; pt = px - 2048; }
    else if (px < 2688) { in = f2; outp = ws + L2_OFS; HW = 4096;  pt = px - 2560; }
    else                { in = f3; outp = ws + L3_OFS; HW = 1024;  pt = px - 2688; }

    __shared__ float tile[32][33];
    const int pix0 = pt * 32;
    const int c0   = blockIdx.y * 32;
    const int b    = blockIdx.z;
    in   += (size_t)b * C_CH * HW;
    outp += (size_t)b * C_CH * HW;
    const int tx = threadIdx.x;   // 0..31
    const int ty = threadIdx.y;   // 0..7

    #pragma unroll
    for (int i = 0; i < 32; i += 8)
        tile[ty + i][tx] = in[(size_t)(c0 + ty + i) * HW + pix0 + tx];
    __syncthreads();

    const int tid2 = ty * 32 + tx;
    const int wpix = tid2 >> 3;      // 0..31
    const int wq   = tid2 & 7;       // channel quad within 32-ch group
    uint2 pk;
    pk.x = pack_bf16x2(tile[wq * 4 + 0][wpix], tile[wq * 4 + 1][wpix]);
    pk.y = pack_bf16x2(tile[wq * 4 + 2][wpix], tile[wq * 4 + 3][wpix]);
    *((uint2*)(outp + (size_t)(pix0 + wpix) * C_CH + c0 + wq * 4)) = pk;
}

// ---------------- sampler v4: pipelined gathers, 32-point tiles ----------------
__global__ __launch_bounds__(256) void mpe_sample_nhwc_bf16_v4(
    const unsigned short* __restrict__ fT,
    const float* __restrict__ rois, const float* __restrict__ points,
    float* __restrict__ out)
{
    const int blk = blockIdx.x;      // n*4 + lvl
    const int n   = blk >> 2;
    const int lvl = blk & 3;

    int H; float inv_stride; size_t lofs;
    if      (lvl == 0) { H = 256; inv_stride = 0.25f;    lofs = L0_OFS; }
    else if (lvl == 1) { H = 128; inv_stride = 0.125f;   lofs = L1_OFS; }
    else if (lvl == 2) { H = 64;  inv_stride = 0.0625f;  lofs = L2_OFS; }
    else               { H = 32;  inv_stride = 0.03125f; lofs = L3_OFS; }
    const int W  = H;
    const int HW = H * W;
    const unsigned short* feat = fT + lofs;

    __shared__ int   s_off[P_PTS][4];
    __shared__ float s_w[P_PTS][4];
    __shared__ float s_t[TILE_P][C_CH];   // 32 KB point-tile staging

    const int tid = threadIdx.x;

    if (tid < P_PTS) {
        const int p = tid;
        const float bx = rois[n * 5 + 0];
        const float x1 = rois[n * 5 + 1];
        const float y1 = rois[n * 5 + 2];
        const float x2 = rois[n * 5 + 3];
        const float y2 = rois[n * 5 + 4];
        const float ptx = points[(n * P_PTS + p) * 2 + 0];
        const float pty = points[(n * P_PTS + p) * 2 + 1];

        const float cx = x1 + ptx * (x2 - x1);
        const float cy = y1 + pty * (y2 - y1);
        const float px = cx * inv_stride - 0.5f;
        const float py = cy * inv_stride - 0.5f;
        const float x0f = floorf(px);
        const float y0f = floorf(py);
        const float wx = px - x0f;
        const float wy = py - y0f;
        const int x0 = (int)x0f;
        const int y0 = (int)y0f;
        const int base = (int)bx * HW;

        #pragma unroll
        for (int k = 0; k < 4; ++k) {
            const int xi = x0 + (k & 1);
            const int yi = y0 + (k >> 1);
            const bool valid = (xi >= 0) & (xi < W) & (yi >= 0) & (yi < H);
            const int xc = min(max(xi, 0), W - 1);
            const int yc = min(max(yi, 0), H - 1);
            const float wk = ((k & 1) ? wx : 1.0f - wx) *
                             ((k >> 1) ? wy : 1.0f - wy);
            s_off[p][k] = base + yc * W + xc;
            s_w[p][k]   = valid ? wk : 0.0f;
        }
    }
    __syncthreads();

    const int wave = tid >> 6;
    const int lane = tid & 63;      // lane = channel-quad (4 bf16 = 8 B)

    // prologue: gather tile 0 (8 points/wave x 4 corners = 32 dwordx2 in flight)
    uint2 v[8][4];
    #pragma unroll
    for (int j = 0; j < 8; ++j) {
        const int pp = wave * 8 + j;
        #pragma unroll
        for (int k = 0; k < 4; ++k)
            v[j][k] = *((const uint2*)(feat + (size_t)s_off[pp][k] * C_CH) + lane);
    }

    for (int tile = 0; tile < P_PTS / TILE_P; ++tile) {
        const int pbase = tile * TILE_P + wave * 8;

        // ---- compute + LDS write (consumes v) ----
        #pragma unroll
        for (int j = 0; j < 8; ++j) {
            const int pp = pbase + j;
            float4 a = make_float4(0.f, 0.f, 0.f, 0.f);
            #pragma unroll
            for (int k = 0; k < 4; ++k) {
                const float wk = s_w[pp][k];
                a.x = fmaf(__uint_as_float(v[j][k].x << 16),         wk, a.x);
                a.y = fmaf(__uint_as_float(v[j][k].x & 0xffff0000u), wk, a.y);
                a.z = fmaf(__uint_as_float(v[j][k].y << 16),         wk, a.z);
                a.w = fmaf(__uint_as_float(v[j][k].y & 0xffff0000u), wk, a.w);
            }
            *((float4*)&s_t[wave * 8 + j][lane * 4]) = a;
        }
        __syncthreads();   // s_t ready

        // ---- issue next tile's gathers early: latency hides under store phase ----
        if (tile < P_PTS / TILE_P - 1) {
            #pragma unroll
            for (int j = 0; j < 8; ++j) {
                const int pp = pbase + TILE_P + j;
                #pragma unroll
                for (int k = 0; k < 4; ++k)
                    v[j][k] = *((const uint2*)(feat + (size_t)s_off[pp][k] * C_CH) + lane);
            }
        }

        // ---- store phase: thread = channel; 128 B contiguous per thread ----
        float* ob = out + ((size_t)n * 1024 + (size_t)lvl * 256 + tid) * P_PTS
                        + tile * TILE_P;
        #pragma unroll
        for (int i = 0; i < TILE_P / 4; ++i) {
            float4 o = make_float4(s_t[i * 4 + 0][tid], s_t[i * 4 + 1][tid],
                                   s_t[i * 4 + 2][tid], s_t[i * 4 + 3][tid]);
            *((float4*)(ob + i * 4)) = o;
        }
        __syncthreads();   // store-phase reads done before next tile overwrites s_t
    }
}

// ---------------- fallback (R1 kernel) if workspace too small ----------------
__global__ __launch_bounds__(256) void mpe_sample_nchw(
    const float* __restrict__ feat0, const float* __restrict__ feat1,
    const float* __restrict__ feat2, const float* __restrict__ feat3,
    const float* __restrict__ rois,  const float* __restrict__ points,
    float* __restrict__ out)
{
    const int blk = blockIdx.x;
    const int n   = blk >> 2;
    const int lvl = blk & 3;

    const float* feat;
    int H; float inv_stride;
    if      (lvl == 0) { feat = feat0; H = 256; inv_stride = 0.25f;    }
    else if (lvl == 1) { feat = feat1; H = 128; inv_stride = 0.125f;   }
    else if (lvl == 2) { feat = feat2; H = 64;  inv_stride = 0.0625f;  }
    else               { feat = feat3; H = 32;  inv_stride = 0.03125f; }
    const int W  = H;
    const int HW = H * W;

    __shared__ int   s_off[4][P_PTS];
    __shared__ float s_w[4][P_PTS];
    const int tid = threadIdx.x;

    if (tid < P_PTS) {
        const int p = tid;
        const float bx = rois[n * 5 + 0];
        const float x1 = rois[n * 5 + 1];
        const float y1 = rois[n * 5 + 2];
        const float x2 = rois[n * 5 + 3];
        const float y2 = rois[n * 5 + 4];
        const float ptx = points[(n * P_PTS + p) * 2 + 0];
        const float pty = points[(n * P_PTS + p) * 2 + 1];
        const float cx = x1 + ptx * (x2 - x1);
        const float cy = y1 + pty * (y2 - y1);
        const float px = cx * inv_stride - 0.5f;
        const float py = cy * inv_stride - 0.5f;
        const float x0f = floorf(px);
        const float y0f = floorf(py);
        const float wx = px - x0f;
        const float wy = py - y0f;
        const int x0 = (int)x0f;
        const int y0 = (int)y0f;
        const int base = (int)bx * C_CH * HW;
        #pragma unroll
        for (int k = 0; k < 4; ++k) {
            const int xi = x0 + (k & 1);
            const int yi = y0 + (k >> 1);
            const bool valid = (xi >= 0) & (xi < W) & (yi >= 0) & (yi < H);
            const int xc = min(max(xi, 0), W - 1);
            const int yc = min(max(yi, 0), H - 1);
            const float wk = ((k & 1) ? wx : 1.0f - wx) *
                             ((k >> 1) ? wy : 1.0f - wy);
            s_off[k][p] = base + yc * W + xc;
            s_w[k][p]   = valid ? wk : 0.0f;
        }
    }
    __syncthreads();

    const int p  = tid & (P_PTS - 1);
    const int c0 = tid >> 7;
    const int   off0 = s_off[0][p], off1 = s_off[1][p],
                off2 = s_off[2][p], off3 = s_off[3][p];
    const float w0 = s_w[0][p], w1 = s_w[1][p],
                w2 = s_w[2][p], w3 = s_w[3][p];
    const float* p0 = feat + off0 + c0 * HW;
    const float* p1 = feat + off1 + c0 * HW;
    const float* p2 = feat + off2 + c0 * HW;
    const float* p3 = feat + off3 + c0 * HW;
    float* po = out + ((size_t)n * 1024 + (size_t)lvl * 256 + c0) * P_PTS + p;
    const int step = 2 * HW;
    #pragma unroll 4
    for (int pass = 0; pass < C_CH / 2; ++pass) {
        *po = p0[0] * w0 + p1[0] * w1 + p2[0] * w2 + p3[0] * w3;
        p0 += step; p1 += step; p2 += step; p3 += step;
        po += 2 * P_PTS;
    }
}

extern "C" void kernel_launch(void* const* d_in, const int* in_sizes, int n_in,
                              void* d_out, int out_size, void* d_ws, size_t ws_size,
                              hipStream_t stream) {
    const float* feat0  = (const float*)d_in[0];
    const float* feat1  = (const float*)d_in[1];
    const float* feat2  = (const float*)d_in[2];
    const float* feat3  = (const float*)d_in[3];
    const float* rois   = (const float*)d_in[4];
    const float* points = (const float*)d_in[5];
    float* out = (float*)d_out;

    if (ws_size >= (size_t)WS_ELEMS_NEEDED * 2u) {
        unsigned short* fT = (unsigned short*)d_ws;
        transpose_all_bf16<<<dim3(2720, 8, 2), dim3(32, 8), 0, stream>>>(
            feat0, feat1, feat2, feat3, fT);
        mpe_sample_nhwc_bf16_v4<<<dim3(N_ROIS * 4), dim3(256), 0, stream>>>(
            fT, rois, points, out);
    } else {
        mpe_sample_nchw<<<dim3(N_ROIS * 4), dim3(256), 0, stream>>>(
            feat0, feat1, feat2, feat3, rois, points, out);
    }
}